// Round 1
// baseline (543.361 us; speedup 1.0000x reference)
//
#include <hip/hip_runtime.h>

// GraphAttentionLayer: B=4, N=4096, F=128, fp32 in/out.
//   w_ij = adj_ij * ( Wh2_j >= -Wh1_i ? P1_i*P2_j : Q1_i*Q2_j )   (softmax scale-invariance
//   + separability of exp(leaky(x+y)) per branch), h = (w @ vp) / rowsum(w), out = leaky(h@Wo^T).
// v4: split-free fused attention. M=64 rows/block, grid=B*64=256 (1 block/CU), full j-range
// per block => h,den complete in-block; fused tail does divide + h@Wo^T (fp32) + leaky.
// Eliminates h_part/den_part round-trip (~268 MB) and the k_out kernel.

constexpr int B = 4, N = 4096, F = 128;
constexpr int BN = B * N;
constexpr int BK = 64;
constexpr int NIT = N / BK;   // 64 iterations over full j-range
#define ALPHA 0.1f

using float4v = __attribute__((ext_vector_type(4))) float;
using short8 = __attribute__((ext_vector_type(8))) short;

__device__ __forceinline__ float leaky(float x) { return x >= 0.f ? x : ALPHA * x; }
__device__ __forceinline__ unsigned short f2bf(float x) {  // RNE float->bf16
    unsigned u = __float_as_uint(x);
    u = (u + 0x7FFFu + ((u >> 16) & 1u)) >> 16;
    return (unsigned short)u;
}
// pack two floats -> two RNE bf16 in one dword: {bf(hi)[31:16], bf(lo)[15:0]}
__device__ __forceinline__ unsigned pack_bf2(float lo, float hi) {
    unsigned a = __float_as_uint(lo), b2 = __float_as_uint(hi);
    a = a + 0x7FFFu + ((a >> 16) & 1u);
    b2 = b2 + 0x7FFFu + ((b2 >> 16) & 1u);
    return __builtin_amdgcn_perm(b2, a, 0x07060302u);  // bytes: b2[3],b2[2],a[3],a[2]
}

// ---------------- K0: c1, c2, d1, d2 ----------------
__global__ void k_prep(const float* __restrict__ Wq_w, const float* __restrict__ Wq_b,
                       const float* __restrict__ Wk_w, const float* __restrict__ Wk_b,
                       const float* __restrict__ a, float* __restrict__ c1,
                       float* __restrict__ c2, float* __restrict__ d12) {
    __shared__ float as[2 * F];
    __shared__ float red[2 * F];
    int t = threadIdx.x;  // 256
    as[t] = a[t];
    __syncthreads();
    int f = t & 127;
    const float* W = (t < F) ? Wq_w : Wk_w;
    const float* ao = (t < F) ? as : as + F;
    float s = 0.f;
#pragma unroll 8
    for (int o = 0; o < F; o++) s = fmaf(W[o * F + f], ao[o], s);
    if (t < F) c1[f] = s; else c2[f] = s;
    red[t] = (t < F) ? Wq_b[f] * as[f] : Wk_b[f] * as[F + f];
    __syncthreads();
    for (int st = 64; st > 0; st >>= 1) {
        if (f < st) red[t] += red[t + st];
        __syncthreads();
    }
    if (t == 0) d12[0] = red[0];
    if (t == F) d12[1] = red[F];
}

// ---------------- K1: Wh1, Wh2 ----------------
__global__ void k_wh(const float* __restrict__ q, const float* __restrict__ k,
                     const float* __restrict__ c1, const float* __restrict__ c2,
                     const float* __restrict__ d12,
                     float* __restrict__ Wh1, float* __restrict__ Wh2) {
    __shared__ float c1s[F], c2s[F];
    int t = threadIdx.x;
    if (t < F) c1s[t] = c1[t]; else c2s[t - F] = c2[t - F];
    __syncthreads();
    int row = blockIdx.x * 8 + (t >> 5);
    int lane = t & 31;
    float4 q4 = reinterpret_cast<const float4*>(q)[row * 32 + lane];
    float4 k4 = reinterpret_cast<const float4*>(k)[row * 32 + lane];
    float s1 = q4.x * c1s[lane * 4 + 0] + q4.y * c1s[lane * 4 + 1] +
               q4.z * c1s[lane * 4 + 2] + q4.w * c1s[lane * 4 + 3];
    float s2 = k4.x * c2s[lane * 4 + 0] + k4.y * c2s[lane * 4 + 1] +
               k4.z * c2s[lane * 4 + 2] + k4.w * c2s[lane * 4 + 3];
    for (int m = 16; m > 0; m >>= 1) { s1 += __shfl_xor(s1, m); s2 += __shfl_xor(s2, m); }
    if (lane == 0) { Wh1[row] = s1 + d12[0]; Wh2[row] = s2 + d12[1]; }
}

// ---------------- K1b: per-batch max of Wh2 ----------------
__global__ void k_max2(const float* __restrict__ Wh2, float* __restrict__ M2) {
    int b = blockIdx.x, t = threadIdx.x;
    float m = -1e30f;
    for (int i = t; i < N; i += 256) m = fmaxf(m, Wh2[b * N + i]);
    __shared__ float red[256];
    red[t] = m;
    __syncthreads();
    for (int s = 128; s > 0; s >>= 1) { if (t < s) red[t] = fmaxf(red[t], red[t + s]); __syncthreads(); }
    if (t == 0) M2[b] = red[0];
}

// ---------------- K1c: exp tables ----------------
__global__ void k_tab(const float* __restrict__ Wh1, const float* __restrict__ Wh2,
                      const float* __restrict__ M2,
                      float* __restrict__ P1, float* __restrict__ Q1,
                      float* __restrict__ P2, float* __restrict__ Q2) {
    int i = blockIdx.x * 256 + threadIdx.x;
    int b = i >> 12;  // N = 4096
    float w1 = Wh1[i], w2 = Wh2[i];
    float mi = leaky(w1 + M2[b]);  // per-row shift (cancels in h; range only)
    P1[i] = __expf(w1 - mi);
    Q1[i] = __expf(ALPHA * w1 - mi);
    P2[i] = __expf(w2);
    Q2[i] = __expf(ALPHA * w2);
}

// ---------------- K2: vpT = bf16( (v @ Wv^T + bv)^T ), layout [B][F][N] ----------------
__global__ __launch_bounds__(256) void k_vp(const float* __restrict__ v,
                                            const float* __restrict__ Wv_w,
                                            const float* __restrict__ Wv_b,
                                            unsigned short* __restrict__ vpT) {
    __shared__ float vs[32][F];            // 16 KB
    __shared__ float Ws[F][129];           // 66 KB, pad -> conflict-free column reads
    __shared__ unsigned short ts[F][40];   // 10 KB transpose tile (pad 8)
    int t = threadIdx.x;
    int row0g = blockIdx.x * 32;           // flat row in [0, BN)
    int b = row0g >> 12;
    int row0 = row0g & (N - 1);
    {
        const float4* src = reinterpret_cast<const float4*>(v + row0g * F);
        float4* dst = reinterpret_cast<float4*>(&vs[0][0]);
#pragma unroll
        for (int u = 0; u < 4; u++) dst[u * 256 + t] = src[u * 256 + t];
    }
    {
        const float4* src = reinterpret_cast<const float4*>(Wv_w);
#pragma unroll
        for (int u = 0; u < 16; u++) {
            int unit = u * 256 + t;
            int r = unit >> 5, s = unit & 31;
            float4 val = src[unit];
            Ws[r][s * 4 + 0] = val.x; Ws[r][s * 4 + 1] = val.y;
            Ws[r][s * 4 + 2] = val.z; Ws[r][s * 4 + 3] = val.w;
        }
    }
    int f = t & 127, g = t >> 7;
    float bias = Wv_b[f];
    __syncthreads();
    float acc[16];
#pragma unroll
    for (int r = 0; r < 16; r++) acc[r] = bias;
    for (int kk = 0; kk < F; kk++) {
        float wk = Ws[f][kk];
#pragma unroll
        for (int r = 0; r < 16; r++) acc[r] = fmaf(vs[g * 16 + r][kk], wk, acc[r]);
    }
#pragma unroll
    for (int r = 0; r < 16; r++) ts[f][g * 16 + r] = f2bf(acc[r]);
    __syncthreads();
    int fr = t >> 1, hseg = t & 1;
    uint4 d0 = *reinterpret_cast<uint4*>(&ts[fr][hseg * 16]);
    uint4 d1 = *reinterpret_cast<uint4*>(&ts[fr][hseg * 16 + 8]);
    unsigned short* dst = vpT + ((size_t)(b * F + fr) * N + row0 + hseg * 16);
    *reinterpret_cast<uint4*>(dst) = d0;
    *reinterpret_cast<uint4*>(dst + 8) = d1;
}

// ---------------- K3: fused MFMA attention + output GEMM ----------------
// M=64 rows/block, grid = B*64 = 256. Loop phase: bs dbuf (36.9 KB) + full-N j-tables
// (48 KB) = 85 KB. Tail phase (same LDS, re-purposed after last barrier): hs[64][129]
// (33 KB) + Wo[128][129] (66 KB) = 99 KB. 1 block/CU.
constexpr int LDS_BS_BYTES = 2 * F * 72 * 2;                 // 36864
constexpr int LDS_LOOP_BYTES = LDS_BS_BYTES + 3 * N * 4;     // 86016
constexpr int LDS_TAIL_BYTES = 64 * 129 * 4 + F * 129 * 4;   // 99072
constexpr int LDS_BYTES = LDS_TAIL_BYTES;                    // max(86016, 99072)

__global__ __launch_bounds__(256, 1) void k_attn(
    const unsigned short* __restrict__ vpT, const int* __restrict__ adj,
    const float* __restrict__ Wh1, const float* __restrict__ P1, const float* __restrict__ Q1,
    const float* __restrict__ P2, const float* __restrict__ Q2, const float* __restrict__ Wh2,
    const float* __restrict__ Wo_w, float* __restrict__ out) {
    __shared__ __align__(16) char smem[LDS_BYTES];
    auto bs = reinterpret_cast<unsigned short(*)[F][72]>(smem);   // [2][F][72]
    float* sP2 = reinterpret_cast<float*>(smem + LDS_BS_BYTES);
    float* sQ2 = sP2 + N;
    float* sW2 = sQ2 + N;

    int t = threadIdx.x;
    int idx = blockIdx.x;            // 256 = B * 64 tiles
    int tile = idx & 63;
    int b = idx >> 6;
    int i0 = tile * 64;
    int widx = t >> 6, lane = t & 63, m = lane & 15, q = lane >> 4;
    int r0 = i0 + widx * 16;         // wave's 16 rows

    {  // preload P2/Q2/W2 for the full batch row (3 x 16 KB), L2-hot across blocks
        const float4* gp = reinterpret_cast<const float4*>(P2 + (size_t)b * N);
        const float4* gq = reinterpret_cast<const float4*>(Q2 + (size_t)b * N);
        const float4* gw = reinterpret_cast<const float4*>(Wh2 + (size_t)b * N);
        float4* dp = reinterpret_cast<float4*>(sP2);
        float4* dq = reinterpret_cast<float4*>(sQ2);
        float4* dw = reinterpret_cast<float4*>(sW2);
#pragma unroll
        for (int u = 0; u < 4; u++) {
            dp[u * 256 + t] = gp[u * 256 + t];
            dq[u * 256 + t] = gq[u * 256 + t];
            dw[u * 256 + t] = gw[u * 256 + t];
        }
    }

    int gi0 = b * N + r0 + m;        // this lane's row
    float p1a = P1[gi0], q1a = Q1[gi0], t1a = -Wh1[gi0];

    const unsigned short* vb = vpT + (size_t)b * F * N;
    const int* adjbase = adj + (size_t)gi0 * N + q * 8;  // + it*64 + kh*32

    uint4 sreg[4];
    int4 aregA[4], aregB[4];  // [kh*2 + {0,1}]

    auto load_stage = [&](int it) {
#pragma unroll
        for (int u = 0; u < 4; u++) {
            int unit = u * 256 + t;
            int r = unit >> 3, s = unit & 7;
            sreg[u] = *reinterpret_cast<const uint4*>(vb + (size_t)r * N + it * BK + s * 8);
        }
    };
    auto write_stage = [&](int pb) {
#pragma unroll
        for (int u = 0; u < 4; u++) {
            int unit = u * 256 + t;
            int r = unit >> 3, s = unit & 7;
            *reinterpret_cast<uint4*>(&bs[pb][r][s * 8]) = sreg[u];
        }
    };
    auto load_adj = [&](int it, int4* ar) {
#pragma unroll
        for (int kh = 0; kh < 2; kh++) {
            const int* p = adjbase + it * BK + kh * 32;
            ar[kh * 2 + 0] = *reinterpret_cast<const int4*>(p);
            ar[kh * 2 + 1] = *reinterpret_cast<const int4*>(p + 4);
        }
    };

    float4v acc0[8];
#pragma unroll
    for (int nt = 0; nt < 8; nt++) acc0[nt] = (float4v){0.f, 0.f, 0.f, 0.f};
    float den0 = 0.f;

    // w-gen: 8 masked-selected weights -> bf16 A-frag
    auto gen_af = [&](const int4& a0, const int4& a1, const float4& x2a, const float4& x2b,
                      const float4& p2a, const float4& p2b, const float4& q2a, const float4& q2b,
                      float p1, float q1, float t1, float& den) -> short8 {
        float w0 = a0.x ? ((x2a.x >= t1) ? p1 * p2a.x : q1 * q2a.x) : 0.f;
        float w1 = a0.y ? ((x2a.y >= t1) ? p1 * p2a.y : q1 * q2a.y) : 0.f;
        float w2 = a0.z ? ((x2a.z >= t1) ? p1 * p2a.z : q1 * q2a.z) : 0.f;
        float w3 = a0.w ? ((x2a.w >= t1) ? p1 * p2a.w : q1 * q2a.w) : 0.f;
        float w4 = a1.x ? ((x2b.x >= t1) ? p1 * p2b.x : q1 * q2b.x) : 0.f;
        float w5 = a1.y ? ((x2b.y >= t1) ? p1 * p2b.y : q1 * q2b.y) : 0.f;
        float w6 = a1.z ? ((x2b.z >= t1) ? p1 * p2b.z : q1 * q2b.z) : 0.f;
        float w7 = a1.w ? ((x2b.w >= t1) ? p1 * p2b.w : q1 * q2b.w) : 0.f;
        den += ((w0 + w1) + (w2 + w3)) + ((w4 + w5) + (w6 + w7));
        union { short8 s; uint4 u; } r;
        r.u.x = pack_bf2(w0, w1); r.u.y = pack_bf2(w2, w3);
        r.u.z = pack_bf2(w4, w5); r.u.w = pack_bf2(w6, w7);
        return r.s;
    };

    auto body = [&](int it, int4* cur, int4* nxt, int pb) {
        if (it + 1 < NIT) {  // prefetch next iteration (latency hidden under compute)
            load_stage(it + 1);
            load_adj(it + 1, nxt);
        }
#pragma unroll
        for (int kh = 0; kh < 2; kh++) {
            int jl = it * BK + kh * 32 + q * 8;
            float4 x2a = *reinterpret_cast<const float4*>(&sW2[jl]);
            float4 x2b = *reinterpret_cast<const float4*>(&sW2[jl + 4]);
            float4 p2a = *reinterpret_cast<const float4*>(&sP2[jl]);
            float4 p2b = *reinterpret_cast<const float4*>(&sP2[jl + 4]);
            float4 q2a = *reinterpret_cast<const float4*>(&sQ2[jl]);
            float4 q2b = *reinterpret_cast<const float4*>(&sQ2[jl + 4]);
            short8 af0 = gen_af(cur[kh * 2 + 0], cur[kh * 2 + 1], x2a, x2b, p2a, p2b, q2a, q2b,
                                p1a, q1a, t1a, den0);
#pragma unroll
            for (int nt = 0; nt < 8; nt++) {
                short8 bf = *reinterpret_cast<const short8*>(&bs[pb][nt * 16 + m][kh * 32 + q * 8]);
                acc0[nt] = __builtin_amdgcn_mfma_f32_16x16x32_bf16(af0, bf, acc0[nt], 0, 0, 0);
            }
        }
        if (it + 1 < NIT) write_stage(pb ^ 1);
        __syncthreads();
    };

    // prologue
    load_stage(0);
    load_adj(0, aregA);
    write_stage(0);
    __syncthreads();

#pragma unroll 1
    for (int ith = 0; ith < NIT / 2; ith++) {
        body(ith * 2 + 0, aregA, aregB, 0);
        body(ith * 2 + 1, aregB, aregA, 1);
    }
    // last body ended with __syncthreads(): all waves done reading bs/sP2/sQ2/sW2.

    // full denominator per row (reduce over q quarters)
    den0 += __shfl_xor(den0, 16);
    den0 += __shfl_xor(den0, 32);

    // ---- fused tail: divide + h @ Wo^T (fp32) + leaky, LDS re-purposed ----
    float (*hs)[129] = reinterpret_cast<float(*)[129]>(smem);                 // [64][129]
    float (*Ws)[129] = reinterpret_cast<float(*)[129]>(smem + 64 * 129 * 4);  // [F][129]

    {  // stage Wo (64 KB, L2-hot)
        const float4* src = reinterpret_cast<const float4*>(Wo_w);
#pragma unroll
        for (int u = 0; u < 16; u++) {
            int unit = u * 256 + t;
            int r = unit >> 5, s = unit & 31;
            float4 val = src[unit];
            Ws[r][s * 4 + 0] = val.x; Ws[r][s * 4 + 1] = val.y;
            Ws[r][s * 4 + 2] = val.z; Ws[r][s * 4 + 3] = val.w;
        }
    }
    // h/den into hs. C/D layout: row = q*4+reg (within 16-tile), col = nt*16+m.
#pragma unroll
    for (int r = 0; r < 4; r++) {
        float inv = 1.f / __shfl(den0, q * 4 + r);  // den for row q*4+r lives at lane m=q*4+r
#pragma unroll
        for (int nt = 0; nt < 8; nt++)
            hs[widx * 16 + q * 4 + r][nt * 16 + m] = acc0[nt][r] * inv;
    }
    __syncthreads();

    int f = t & 127, g = t >> 7;
    float acc[32];
#pragma unroll
    for (int r = 0; r < 32; r++) acc[r] = 0.f;
    for (int kk = 0; kk < F; kk++) {
        float wk = Ws[f][kk];
#pragma unroll
        for (int r = 0; r < 32; r++) acc[r] = fmaf(hs[g * 32 + r][kk], wk, acc[r]);
    }
    size_t obase = (size_t)(b * N + i0 + g * 32) * F + f;
#pragma unroll
    for (int r = 0; r < 32; r++) out[obase + (size_t)r * F] = leaky(acc[r]);
}

extern "C" void kernel_launch(void* const* d_in, const int* in_sizes, int n_in,
                              void* d_out, int out_size, void* d_ws, size_t ws_size,
                              hipStream_t stream) {
    const float* q    = (const float*)d_in[0];
    const float* k    = (const float*)d_in[1];
    const float* v    = (const float*)d_in[2];
    const int*   adj  = (const int*)d_in[3];
    const float* Wq_w = (const float*)d_in[4];
    const float* Wq_b = (const float*)d_in[5];
    const float* Wk_w = (const float*)d_in[6];
    const float* Wk_b = (const float*)d_in[7];
    const float* Wv_w = (const float*)d_in[8];
    const float* Wv_b = (const float*)d_in[9];
    const float* a    = (const float*)d_in[10];
    const float* Wo_w = (const float*)d_in[11];
    float* out = (float*)d_out;
    float* ws = (float*)d_ws;

    unsigned short* vpT = (unsigned short*)ws;        // BN*F bf16 = BN*F/2 floats
    float* Wh1 = ws + BN * F / 2;
    float* Wh2 = Wh1 + BN;
    float* P1  = Wh2 + BN;
    float* Q1  = P1 + BN;
    float* P2  = Q1 + BN;
    float* Q2  = P2 + BN;
    float* c1  = Q2 + BN;                             // F
    float* c2  = c1 + F;                              // F
    float* d12 = c2 + F;                              // 2
    float* M2  = d12 + 2;                             // B

    k_prep<<<1, 256, 0, stream>>>(Wq_w, Wq_b, Wk_w, Wk_b, a, c1, c2, d12);
    k_wh<<<BN / 8, 256, 0, stream>>>(q, k, c1, c2, d12, Wh1, Wh2);
    k_max2<<<B, 256, 0, stream>>>(Wh2, M2);
    k_tab<<<BN / 256, 256, 0, stream>>>(Wh1, Wh2, M2, P1, Q1, P2, Q2);
    k_vp<<<BN / 32, 256, 0, stream>>>(v, Wv_w, Wv_b, vpT);
    k_attn<<<B * 64, 256, 0, stream>>>(vpT, adj, Wh1, P1, Q1, P2, Q2, Wh2, Wo_w, out);
}

// Round 3
// 511.031 us; speedup vs baseline: 1.0633x; 1.0633x over previous
//
#include <hip/hip_runtime.h>

// GraphAttentionLayer: B=4, N=4096, F=128, fp32 in/out.
//   w_ij = adj_ij * ( Wh2_j >= -Wh1_i ? P1_i*P2_j : Q1_i*Q2_j )   (softmax scale-invariance
//   + separability of exp(leaky(x+y)) per branch), h = (w @ vp) / rowsum(w), out = leaky(h@Wo^T).
// v5 (resubmit; round-2 bench was an infra failure, no kernel evidence): fused attention,
// 512-thread blocks (8 waves/CU = 2 waves/SIMD; v4's 256-thr/1-wave-per-SIMD was latency-bound
// at 213us, Occ 11%). M=64 rows/block, grid=B*64=256, full j-range per block.
// Wave w: row-tile rt=w>>1 (16 rows), j-half kh=w&1 (32 of 64 j per iter). den/h halves combined
// in LDS epilogue; fused tail does divide + h@Wo^T (fp32) + leaky on all 512 threads.

constexpr int B = 4, N = 4096, F = 128;
constexpr int BN = B * N;
constexpr int BK = 64;
constexpr int NIT = N / BK;   // 64 iterations over full j-range
#define ALPHA 0.1f

using float4v = __attribute__((ext_vector_type(4))) float;
using short8 = __attribute__((ext_vector_type(8))) short;

__device__ __forceinline__ float leaky(float x) { return x >= 0.f ? x : ALPHA * x; }
__device__ __forceinline__ unsigned short f2bf(float x) {  // RNE float->bf16
    unsigned u = __float_as_uint(x);
    u = (u + 0x7FFFu + ((u >> 16) & 1u)) >> 16;
    return (unsigned short)u;
}
// pack two floats -> two RNE bf16 in one dword: {bf(hi)[31:16], bf(lo)[15:0]}
__device__ __forceinline__ unsigned pack_bf2(float lo, float hi) {
    unsigned a = __float_as_uint(lo), b2 = __float_as_uint(hi);
    a = a + 0x7FFFu + ((a >> 16) & 1u);
    b2 = b2 + 0x7FFFu + ((b2 >> 16) & 1u);
    return __builtin_amdgcn_perm(b2, a, 0x07060302u);  // bytes: b2[3],b2[2],a[3],a[2]
}

// ---------------- K0: c1, c2, d1, d2 ----------------
__global__ void k_prep(const float* __restrict__ Wq_w, const float* __restrict__ Wq_b,
                       const float* __restrict__ Wk_w, const float* __restrict__ Wk_b,
                       const float* __restrict__ a, float* __restrict__ c1,
                       float* __restrict__ c2, float* __restrict__ d12) {
    __shared__ float as[2 * F];
    __shared__ float red[2 * F];
    int t = threadIdx.x;  // 256
    as[t] = a[t];
    __syncthreads();
    int f = t & 127;
    const float* W = (t < F) ? Wq_w : Wk_w;
    const float* ao = (t < F) ? as : as + F;
    float s = 0.f;
#pragma unroll 8
    for (int o = 0; o < F; o++) s = fmaf(W[o * F + f], ao[o], s);
    if (t < F) c1[f] = s; else c2[f] = s;
    red[t] = (t < F) ? Wq_b[f] * as[f] : Wk_b[f] * as[F + f];
    __syncthreads();
    for (int st = 64; st > 0; st >>= 1) {
        if (f < st) red[t] += red[t + st];
        __syncthreads();
    }
    if (t == 0) d12[0] = red[0];
    if (t == F) d12[1] = red[F];
}

// ---------------- K1: Wh1, Wh2 ----------------
__global__ void k_wh(const float* __restrict__ q, const float* __restrict__ k,
                     const float* __restrict__ c1, const float* __restrict__ c2,
                     const float* __restrict__ d12,
                     float* __restrict__ Wh1, float* __restrict__ Wh2) {
    __shared__ float c1s[F], c2s[F];
    int t = threadIdx.x;
    if (t < F) c1s[t] = c1[t]; else c2s[t - F] = c2[t - F];
    __syncthreads();
    int row = blockIdx.x * 8 + (t >> 5);
    int lane = t & 31;
    float4 q4 = reinterpret_cast<const float4*>(q)[row * 32 + lane];
    float4 k4 = reinterpret_cast<const float4*>(k)[row * 32 + lane];
    float s1 = q4.x * c1s[lane * 4 + 0] + q4.y * c1s[lane * 4 + 1] +
               q4.z * c1s[lane * 4 + 2] + q4.w * c1s[lane * 4 + 3];
    float s2 = k4.x * c2s[lane * 4 + 0] + k4.y * c2s[lane * 4 + 1] +
               k4.z * c2s[lane * 4 + 2] + k4.w * c2s[lane * 4 + 3];
    for (int m = 16; m > 0; m >>= 1) { s1 += __shfl_xor(s1, m); s2 += __shfl_xor(s2, m); }
    if (lane == 0) { Wh1[row] = s1 + d12[0]; Wh2[row] = s2 + d12[1]; }
}

// ---------------- K1b: per-batch max of Wh2 ----------------
__global__ void k_max2(const float* __restrict__ Wh2, float* __restrict__ M2) {
    int b = blockIdx.x, t = threadIdx.x;
    float m = -1e30f;
    for (int i = t; i < N; i += 256) m = fmaxf(m, Wh2[b * N + i]);
    __shared__ float red[256];
    red[t] = m;
    __syncthreads();
    for (int s = 128; s > 0; s >>= 1) { if (t < s) red[t] = fmaxf(red[t], red[t + s]); __syncthreads(); }
    if (t == 0) M2[b] = red[0];
}

// ---------------- K1c: exp tables ----------------
__global__ void k_tab(const float* __restrict__ Wh1, const float* __restrict__ Wh2,
                      const float* __restrict__ M2,
                      float* __restrict__ P1, float* __restrict__ Q1,
                      float* __restrict__ P2, float* __restrict__ Q2) {
    int i = blockIdx.x * 256 + threadIdx.x;
    int b = i >> 12;  // N = 4096
    float w1 = Wh1[i], w2 = Wh2[i];
    float mi = leaky(w1 + M2[b]);  // per-row shift (cancels in h; range only)
    P1[i] = __expf(w1 - mi);
    Q1[i] = __expf(ALPHA * w1 - mi);
    P2[i] = __expf(w2);
    Q2[i] = __expf(ALPHA * w2);
}

// ---------------- K2: vpT = bf16( (v @ Wv^T + bv)^T ), layout [B][F][N] ----------------
__global__ __launch_bounds__(256) void k_vp(const float* __restrict__ v,
                                            const float* __restrict__ Wv_w,
                                            const float* __restrict__ Wv_b,
                                            unsigned short* __restrict__ vpT) {
    __shared__ float vs[32][F];            // 16 KB
    __shared__ float Ws[F][129];           // 66 KB, pad -> conflict-free column reads
    __shared__ unsigned short ts[F][40];   // 10 KB transpose tile (pad 8)
    int t = threadIdx.x;
    int row0g = blockIdx.x * 32;           // flat row in [0, BN)
    int b = row0g >> 12;
    int row0 = row0g & (N - 1);
    {
        const float4* src = reinterpret_cast<const float4*>(v + row0g * F);
        float4* dst = reinterpret_cast<float4*>(&vs[0][0]);
#pragma unroll
        for (int u = 0; u < 4; u++) dst[u * 256 + t] = src[u * 256 + t];
    }
    {
        const float4* src = reinterpret_cast<const float4*>(Wv_w);
#pragma unroll
        for (int u = 0; u < 16; u++) {
            int unit = u * 256 + t;
            int r = unit >> 5, s = unit & 31;
            float4 val = src[unit];
            Ws[r][s * 4 + 0] = val.x; Ws[r][s * 4 + 1] = val.y;
            Ws[r][s * 4 + 2] = val.z; Ws[r][s * 4 + 3] = val.w;
        }
    }
    int f = t & 127, g = t >> 7;
    float bias = Wv_b[f];
    __syncthreads();
    float acc[16];
#pragma unroll
    for (int r = 0; r < 16; r++) acc[r] = bias;
    for (int kk = 0; kk < F; kk++) {
        float wk = Ws[f][kk];
#pragma unroll
        for (int r = 0; r < 16; r++) acc[r] = fmaf(vs[g * 16 + r][kk], wk, acc[r]);
    }
#pragma unroll
    for (int r = 0; r < 16; r++) ts[f][g * 16 + r] = f2bf(acc[r]);
    __syncthreads();
    int fr = t >> 1, hseg = t & 1;
    uint4 d0 = *reinterpret_cast<uint4*>(&ts[fr][hseg * 16]);
    uint4 d1 = *reinterpret_cast<uint4*>(&ts[fr][hseg * 16 + 8]);
    unsigned short* dst = vpT + ((size_t)(b * F + fr) * N + row0 + hseg * 16);
    *reinterpret_cast<uint4*>(dst) = d0;
    *reinterpret_cast<uint4*>(dst + 8) = d1;
}

// ---------------- K3: fused MFMA attention + output GEMM, 512 threads ----------------
// Loop LDS: bs dbuf (36.9 KB) + full-N j-tables (48 KB) = 85 KB.
// Tail LDS (re-purposed): hs[64][129] (33 KB) + Wo[128][129] (66 KB) = 99 KB. + denb 512 B.
constexpr int LDS_BS_BYTES = 2 * F * 72 * 2;                 // 36864
constexpr int LDS_TAIL_BYTES = 64 * 129 * 4 + F * 129 * 4;   // 99072
constexpr int LDS_BYTES = LDS_TAIL_BYTES + 512;              // + denb

__global__ __launch_bounds__(512, 1) void k_attn(
    const unsigned short* __restrict__ vpT, const int* __restrict__ adj,
    const float* __restrict__ Wh1, const float* __restrict__ P1, const float* __restrict__ Q1,
    const float* __restrict__ P2, const float* __restrict__ Q2, const float* __restrict__ Wh2,
    const float* __restrict__ Wo_w, float* __restrict__ out) {
    __shared__ __align__(16) char smem[LDS_BYTES];
    auto bs = reinterpret_cast<unsigned short(*)[F][72]>(smem);   // [2][F][72]
    float* sP2 = reinterpret_cast<float*>(smem + LDS_BS_BYTES);
    float* sQ2 = sP2 + N;
    float* sW2 = sQ2 + N;
    float* denb = reinterpret_cast<float*>(smem + LDS_TAIL_BYTES);  // [4][2][16]

    int t = threadIdx.x;             // 512
    int idx = blockIdx.x;            // 256 = B * 64 tiles
    int tile = idx & 63;
    int b = idx >> 6;
    int i0 = tile * 64;
    int widx = t >> 6, lane = t & 63, m = lane & 15, q = lane >> 4;
    int rt = widx >> 1;              // row-tile 0..3
    int kh = widx & 1;               // j-half 0..1
    int r0 = i0 + rt * 16;           // wave's 16 rows

    {  // preload P2/Q2/W2 for the full batch row (3 x 16 KB), L2-hot across blocks
        const float4* gp = reinterpret_cast<const float4*>(P2 + (size_t)b * N);
        const float4* gq = reinterpret_cast<const float4*>(Q2 + (size_t)b * N);
        const float4* gw = reinterpret_cast<const float4*>(Wh2 + (size_t)b * N);
        float4* dp = reinterpret_cast<float4*>(sP2);
        float4* dq = reinterpret_cast<float4*>(sQ2);
        float4* dw = reinterpret_cast<float4*>(sW2);
#pragma unroll
        for (int u = 0; u < 2; u++) {
            dp[u * 512 + t] = gp[u * 512 + t];
            dq[u * 512 + t] = gq[u * 512 + t];
            dw[u * 512 + t] = gw[u * 512 + t];
        }
    }

    int gi0 = b * N + r0 + m;        // this lane's row
    float p1a = P1[gi0], q1a = Q1[gi0], t1a = -Wh1[gi0];

    const unsigned short* vb = vpT + (size_t)b * F * N;
    const int* adjbase = adj + (size_t)gi0 * N + kh * 32 + q * 8;  // + it*64

    uint4 sreg[2];
    int4 aregA[2], aregB[2];

    auto load_stage = [&](int it) {
#pragma unroll
        for (int u = 0; u < 2; u++) {
            int unit = u * 512 + t;
            int r = unit >> 3, s = unit & 7;
            sreg[u] = *reinterpret_cast<const uint4*>(vb + (size_t)r * N + it * BK + s * 8);
        }
    };
    auto write_stage = [&](int pb) {
#pragma unroll
        for (int u = 0; u < 2; u++) {
            int unit = u * 512 + t;
            int r = unit >> 3, s = unit & 7;
            *reinterpret_cast<uint4*>(&bs[pb][r][s * 8]) = sreg[u];
        }
    };
    auto load_adj = [&](int it, int4* ar) {
        const int* p = adjbase + it * BK;
        ar[0] = *reinterpret_cast<const int4*>(p);
        ar[1] = *reinterpret_cast<const int4*>(p + 4);
    };

    float4v acc0[8];
#pragma unroll
    for (int nt = 0; nt < 8; nt++) acc0[nt] = (float4v){0.f, 0.f, 0.f, 0.f};
    float den0 = 0.f;

    // w-gen: 8 masked-selected weights -> bf16 A-frag
    auto gen_af = [&](const int4& a0, const int4& a1, const float4& x2a, const float4& x2b,
                      const float4& p2a, const float4& p2b, const float4& q2a, const float4& q2b,
                      float p1, float q1, float t1, float& den) -> short8 {
        float w0 = a0.x ? ((x2a.x >= t1) ? p1 * p2a.x : q1 * q2a.x) : 0.f;
        float w1 = a0.y ? ((x2a.y >= t1) ? p1 * p2a.y : q1 * q2a.y) : 0.f;
        float w2 = a0.z ? ((x2a.z >= t1) ? p1 * p2a.z : q1 * q2a.z) : 0.f;
        float w3 = a0.w ? ((x2a.w >= t1) ? p1 * p2a.w : q1 * q2a.w) : 0.f;
        float w4 = a1.x ? ((x2b.x >= t1) ? p1 * p2b.x : q1 * q2b.x) : 0.f;
        float w5 = a1.y ? ((x2b.y >= t1) ? p1 * p2b.y : q1 * q2b.y) : 0.f;
        float w6 = a1.z ? ((x2b.z >= t1) ? p1 * p2b.z : q1 * q2b.z) : 0.f;
        float w7 = a1.w ? ((x2b.w >= t1) ? p1 * p2b.w : q1 * q2b.w) : 0.f;
        den += ((w0 + w1) + (w2 + w3)) + ((w4 + w5) + (w6 + w7));
        union { short8 s; uint4 u; } r;
        r.u.x = pack_bf2(w0, w1); r.u.y = pack_bf2(w2, w3);
        r.u.z = pack_bf2(w4, w5); r.u.w = pack_bf2(w6, w7);
        return r.s;
    };

    auto body = [&](int it, int4* cur, int4* nxt, int pb) {
        if (it + 1 < NIT) {  // prefetch next iteration (latency hidden under compute)
            load_stage(it + 1);
            load_adj(it + 1, nxt);
        }
        {
            int jl = it * BK + kh * 32 + q * 8;
            float4 x2a = *reinterpret_cast<const float4*>(&sW2[jl]);
            float4 x2b = *reinterpret_cast<const float4*>(&sW2[jl + 4]);
            float4 p2a = *reinterpret_cast<const float4*>(&sP2[jl]);
            float4 p2b = *reinterpret_cast<const float4*>(&sP2[jl + 4]);
            float4 q2a = *reinterpret_cast<const float4*>(&sQ2[jl]);
            float4 q2b = *reinterpret_cast<const float4*>(&sQ2[jl + 4]);
            short8 af0 = gen_af(cur[0], cur[1], x2a, x2b, p2a, p2b, q2a, q2b,
                                p1a, q1a, t1a, den0);
#pragma unroll
            for (int nt = 0; nt < 8; nt++) {
                short8 bf = *reinterpret_cast<const short8*>(&bs[pb][nt * 16 + m][kh * 32 + q * 8]);
                acc0[nt] = __builtin_amdgcn_mfma_f32_16x16x32_bf16(af0, bf, acc0[nt], 0, 0, 0);
            }
        }
        if (it + 1 < NIT) write_stage(pb ^ 1);
        __syncthreads();
    };

    // prologue
    load_stage(0);
    load_adj(0, aregA);
    write_stage(0);
    __syncthreads();

#pragma unroll 1
    for (int ith = 0; ith < NIT / 2; ith++) {
        body(ith * 2 + 0, aregA, aregB, 0);
        body(ith * 2 + 1, aregB, aregA, 1);
    }
    // last body ended with __syncthreads(): all waves done reading bs/sP2/sQ2/sW2.

    // ---- fused tail: combine j-halves, divide, h @ Wo^T (fp32), leaky ----
    float (*hs)[129] = reinterpret_cast<float(*)[129]>(smem);                 // [64][129]
    float (*Ws)[129] = reinterpret_cast<float(*)[129]>(smem + 64 * 129 * 4);  // [F][129]

    {  // stage Wo (64 KB, L2-hot); region disjoint from hs/denb
        const float4* src = reinterpret_cast<const float4*>(Wo_w);
#pragma unroll
        for (int u = 0; u < 8; u++) {
            int unit = u * 512 + t;
            int r = unit >> 5, s = unit & 31;
            float4 val = src[unit];
            Ws[r][s * 4 + 0] = val.x; Ws[r][s * 4 + 1] = val.y;
            Ws[r][s * 4 + 2] = val.z; Ws[r][s * 4 + 3] = val.w;
        }
    }

    // half-denominator per row (reduce over q quarters); every lane ends with row m's half-den
    den0 += __shfl_xor(den0, 16);
    den0 += __shfl_xor(den0, 32);
    if (lane < 16) denb[(rt * 2 + kh) * 16 + m] = den0;

    // C/D layout: row(16-tile) = q*4+reg, col = nt*16+m.
    if (kh == 0) {  // write raw half-sums
#pragma unroll
        for (int r = 0; r < 4; r++)
#pragma unroll
            for (int nt = 0; nt < 8; nt++)
                hs[rt * 16 + q * 4 + r][nt * 16 + m] = acc0[nt][r];
    }
    __syncthreads();
    if (kh == 1) {  // combine + scale by 1/den
#pragma unroll
        for (int r = 0; r < 4; r++) {
            float dfull = denb[(rt * 2 + 0) * 16 + q * 4 + r] + denb[(rt * 2 + 1) * 16 + q * 4 + r];
            float inv = 1.f / dfull;
#pragma unroll
            for (int nt = 0; nt < 8; nt++) {
                int row = rt * 16 + q * 4 + r, col = nt * 16 + m;
                hs[row][col] = (hs[row][col] + acc0[nt][r]) * inv;
            }
        }
    }
    __syncthreads();

    int f = t & 127, g = t >> 7;   // g in 0..3, 16 rows each
    float acc[16];
#pragma unroll
    for (int r = 0; r < 16; r++) acc[r] = 0.f;
    for (int kk = 0; kk < F; kk++) {
        float wk = Ws[f][kk];
#pragma unroll
        for (int r = 0; r < 16; r++) acc[r] = fmaf(hs[g * 16 + r][kk], wk, acc[r]);
    }
    size_t obase = (size_t)(b * N + i0 + g * 16) * F + f;
#pragma unroll
    for (int r = 0; r < 16; r++) out[obase + (size_t)r * F] = leaky(acc[r]);
}

extern "C" void kernel_launch(void* const* d_in, const int* in_sizes, int n_in,
                              void* d_out, int out_size, void* d_ws, size_t ws_size,
                              hipStream_t stream) {
    const float* q    = (const float*)d_in[0];
    const float* k    = (const float*)d_in[1];
    const float* v    = (const float*)d_in[2];
    const int*   adj  = (const int*)d_in[3];
    const float* Wq_w = (const float*)d_in[4];
    const float* Wq_b = (const float*)d_in[5];
    const float* Wk_w = (const float*)d_in[6];
    const float* Wk_b = (const float*)d_in[7];
    const float* Wv_w = (const float*)d_in[8];
    const float* Wv_b = (const float*)d_in[9];
    const float* a    = (const float*)d_in[10];
    const float* Wo_w = (const float*)d_in[11];
    float* out = (float*)d_out;
    float* ws = (float*)d_ws;

    unsigned short* vpT = (unsigned short*)ws;        // BN*F bf16 = BN*F/2 floats
    float* Wh1 = ws + BN * F / 2;
    float* Wh2 = Wh1 + BN;
    float* P1  = Wh2 + BN;
    float* Q1  = P1 + BN;
    float* P2  = Q1 + BN;
    float* Q2  = P2 + BN;
    float* c1  = Q2 + BN;                             // F
    float* c2  = c1 + F;                              // F
    float* d12 = c2 + F;                              // 2
    float* M2  = d12 + 2;                             // B

    k_prep<<<1, 256, 0, stream>>>(Wq_w, Wq_b, Wk_w, Wk_b, a, c1, c2, d12);
    k_wh<<<BN / 8, 256, 0, stream>>>(q, k, c1, c2, d12, Wh1, Wh2);
    k_max2<<<B, 256, 0, stream>>>(Wh2, M2);
    k_tab<<<BN / 256, 256, 0, stream>>>(Wh1, Wh2, M2, P1, Q1, P2, Q2);
    k_vp<<<BN / 32, 256, 0, stream>>>(v, Wv_w, Wv_b, vpT);
    k_attn<<<B * 64, 512, 0, stream>>>(vpT, adj, Wh1, P1, Q1, P2, Q2, Wh2, Wo_w, out);
}